// Round 11
// baseline (254.080 us; speedup 1.0000x reference)
//
#include <hip/hip_runtime.h>

typedef short short8 __attribute__((ext_vector_type(8)));
typedef _Float16 half8 __attribute__((ext_vector_type(8)));
typedef float floatx4 __attribute__((ext_vector_type(4)));
typedef __attribute__((address_space(1))) const void gvoid;
typedef __attribute__((address_space(3))) void svoid;

#define SCALE_POS 2.0f
#define SCALE_NEG 40.0f
#define THRESH 0.5f
#define MARGIN 0.1f
#define EPSV 1e-5f

__device__ __forceinline__ unsigned short f2bf(float f) {
    unsigned u = __float_as_uint(f);
    u += 0x7fffu + ((u >> 16) & 1u);   // round-to-nearest-even
    return (unsigned short)(u >> 16);
}
// order-preserving float<->uint map (no NaNs present)
__device__ __forceinline__ unsigned f2ord(float f) {
    unsigned u = __float_as_uint(f);
    return (u & 0x80000000u) ? ~u : (u | 0x80000000u);
}
__device__ __forceinline__ float ord2f(unsigned e) {
    unsigned v = (e & 0x80000000u) ? (e & 0x7fffffffu) : ~e;
    return __uint_as_float(v);
}

#define ORD_POS_INF 0xff800000u   // f2ord(+inf)
#define ORD_NEG_INF 0x007fffffu   // f2ord(-inf)

// relaxed agent-scope atomics: coherent, NO wbl2/inv fences (R9/R10 lesson:
// ACQ_REL agent RMWs cost ~55ns each in serialized L2 maintenance)
__device__ __forceinline__ unsigned aload_u32(const unsigned* p) {
    return __hip_atomic_load(p, __ATOMIC_RELAXED, __HIP_MEMORY_SCOPE_AGENT);
}
__device__ __forceinline__ void ainc_u32(unsigned* p) {
    __hip_atomic_fetch_add(p, 1u, __ATOMIC_RELAXED, __HIP_MEMORY_SCOPE_AGENT);
}

// ---- kernel 1: fp32 -> bf16 cast + stat/counter init ----
// (separate kernel: its end-of-kernel release flushes the plain fb16 stores
//  to the coherence point — required for cross-XCD global_load_lds reads)
__global__ void k_init(const float* __restrict__ feats,
                       unsigned short* __restrict__ fb16,
                       unsigned* __restrict__ minp, unsigned* __restrict__ maxn,
                       float* __restrict__ psum, float* __restrict__ nsum,
                       unsigned* __restrict__ cnts,
                       int total4, int B) {
    int i = blockIdx.x * blockDim.x + threadIdx.x;
    if (i < total4) {
        float4 v = ((const float4*)feats)[i];
        ushort4 o;
        o.x = f2bf(v.x); o.y = f2bf(v.y); o.z = f2bf(v.z); o.w = f2bf(v.w);
        ((ushort4*)fb16)[i] = o;
    }
    if (i < B) {
        minp[i] = ORD_POS_INF;
        maxn[i] = ORD_NEG_INF;
        psum[i] = 0.f;
        nsum[i] = 0.f;
    }
    if (i < 64) cnts[i] = 0;   // arrive[0..nb-1], done @ 32
}

// =====================================================================
// kernel 2 (primary): FUSED GEMM + stats + gated exp sums + reduction.
// 1056 half-tile blocks x 128 thr (R10's proven GEMM shape, 16 MFMA/
// wave/iter). After stats: relaxed arrival counters per 128-row block
// (uniform target 2*nb); spin with s_sleep; then phase 2 runs on the
// LIVE fp32 accumulators (no fp16 store/reload, no extra dispatch).
// Last block (relaxed done counter) reduces the scalar loss.
// =====================================================================
__global__ void __launch_bounds__(128)
k_fused(const unsigned short* __restrict__ fb16,
        const int* __restrict__ labels,
        unsigned* __restrict__ minp_ord,
        unsigned* __restrict__ maxn_ord,
        float* __restrict__ psum, float* __restrict__ nsum,
        unsigned* __restrict__ arrive, unsigned* __restrict__ done_cnt,
        float* __restrict__ out,
        int D, int nb, int B) {
    __shared__ __align__(16) unsigned short As[128 * 32];  // 8 KB
    __shared__ __align__(16) unsigned short Bs[64 * 32];   // 4 KB
    __shared__ int labR[128], labC[64];
    __shared__ float mpR[128], mnR[128], mpC[64], mnC[64];
    __shared__ float red[2];
    __shared__ unsigned lastflag;

    const int bid = blockIdx.x;
    int t = bid >> 1;
    const int h = bid & 1;
    int rb = 0, rem = t;
    while (rem >= nb - rb) { rem -= nb - rb; ++rb; }
    const int cb = rb + rem;
    const int rowBase = rb * 128;
    const int colBase = cb * 128 + h * 64;
    const bool offd = (rb != cb);

    const int tid = threadIdx.x;        // 0..127
    const int lane = tid & 63;
    const int wave = tid >> 6;          // 0..1 : row half (64 rows each)
    const int q = lane >> 4;
    const int cIn = lane & 15;

    labR[tid] = labels[rowBase + tid];
    if (tid < 64) labC[tid] = labels[colBase + tid];

    // staging: 12 chunks of 1KB (16 rows x 32 cols). Wave handles 6.
    const int srow = lane >> 2;
    const int scol = (lane & 3) * 8;
    const unsigned short* gP[6];
    unsigned short* lP[6];
#pragma unroll
    for (int j = 0; j < 6; ++j) {
        const int c = wave * 6 + j;
        const int base = (c < 8) ? (rowBase + c * 16) : (colBase + (c - 8) * 16);
        gP[j] = fb16 + (size_t)(base + srow) * D + scol;
        lP[j] = ((c < 8) ? (As + c * 512) : (Bs + (c - 8) * 512)) + lane * 8;
    }

    int aOff[4], bOff[4];
#pragma unroll
    for (int i = 0; i < 4; ++i) {
        aOff[i] = (wave * 64 + i * 16 + cIn) * 32 + q * 8;
        bOff[i] = (i * 16 + cIn) * 32 + q * 8;
    }

    floatx4 acc[4][4] = {};

    const int KT = D >> 5;
    for (int kt = 0; kt < KT; ++kt) {
        const int kOff = kt * 32;
        __syncthreads();
#pragma unroll
        for (int j = 0; j < 6; ++j)
            __builtin_amdgcn_global_load_lds((gvoid*)(gP[j] + kOff), (svoid*)lP[j], 16, 0, 0);
        __syncthreads();

        short8 a[4], b[4];
#pragma unroll
        for (int i = 0; i < 4; ++i) a[i] = *(const short8*)(As + aOff[i]);
#pragma unroll
        for (int i = 0; i < 4; ++i) b[i] = *(const short8*)(Bs + bOff[i]);
#pragma unroll
        for (int i = 0; i < 4; ++i)
#pragma unroll
            for (int j = 0; j < 4; ++j)
                acc[i][j] = __builtin_amdgcn_mfma_f32_16x16x32_bf16(a[i], b[j], acc[i][j], 0, 0, 0);
    }

    int rLabv[16];
#pragma unroll
    for (int mi = 0; mi < 4; ++mi)
#pragma unroll
        for (int rr = 0; rr < 4; ++rr)
            rLabv[mi * 4 + rr] = labR[wave * 64 + mi * 16 + q * 4 + rr];
    int cLabv[4];
#pragma unroll
    for (int ni = 0; ni < 4; ++ni)
        cLabv[ni] = labC[ni * 16 + cIn];

    // ---- row stats ----
#pragma unroll
    for (int mi = 0; mi < 4; ++mi)
#pragma unroll
        for (int rr = 0; rr < 4; ++rr) {
            const int rLoc = wave * 64 + mi * 16 + q * 4 + rr;
            const int rLab = rLabv[mi * 4 + rr];
            float vmin = 1e30f, vmax = -1e30f;
#pragma unroll
            for (int ni = 0; ni < 4; ++ni) {
                float s = acc[mi][ni][rr];
                if (rLab == cLabv[ni]) {
                    if (s < 1.0f - EPSV) vmin = fminf(vmin, s);
                } else {
                    vmax = fmaxf(vmax, s);
                }
            }
#pragma unroll
            for (int off = 8; off; off >>= 1) {
                vmin = fminf(vmin, __shfl_xor(vmin, off, 16));
                vmax = fmaxf(vmax, __shfl_xor(vmax, off, 16));
            }
            if (cIn == 0) {
                if (vmin < 1e30f) atomicMin(&minp_ord[rowBase + rLoc], f2ord(vmin));
                if (vmax > -1e30f) atomicMax(&maxn_ord[rowBase + rLoc], f2ord(vmax));
            }
        }

    // ---- col stats via symmetry (off-diagonal tiles only) ----
    if (offd) {
#pragma unroll
        for (int ni = 0; ni < 4; ++ni) {
            const int cLab = cLabv[ni];
            float vmin = 1e30f, vmax = -1e30f;
#pragma unroll
            for (int mi = 0; mi < 4; ++mi)
#pragma unroll
                for (int rr = 0; rr < 4; ++rr) {
                    float s = acc[mi][ni][rr];
                    if (rLabv[mi * 4 + rr] == cLab) {
                        if (s < 1.0f - EPSV) vmin = fminf(vmin, s);
                    } else {
                        vmax = fmaxf(vmax, s);
                    }
                }
            vmin = fminf(vmin, __shfl_xor(vmin, 16, 64));
            vmin = fminf(vmin, __shfl_xor(vmin, 32, 64));
            vmax = fmaxf(vmax, __shfl_xor(vmax, 16, 64));
            vmax = fmaxf(vmax, __shfl_xor(vmax, 32, 64));
            if (q == 0) {
                const int cLoc = ni * 16 + cIn;
                if (vmin < 1e30f) atomicMin(&minp_ord[colBase + cLoc], f2ord(vmin));
                if (vmax > -1e30f) atomicMax(&maxn_ord[colBase + cLoc], f2ord(vmax));
            }
        }
    }

    // ---- arrival sync (relaxed agent atomics — no cache flushes) ----
    // Each 128-row block r receives exactly 2*nb increments:
    //   2 from its diagonal halves (row stats), 2*(nb-1-r) from tiles to
    //   its right (row stats), 2*r from tiles above (col stats).
    // __syncthreads() drains vmcnt for ALL waves -> this block's stat
    // atomics are complete at the coherence point before the increment.
    const unsigned target = 2u * (unsigned)nb;
    __syncthreads();
    if (tid == 0) {
        ainc_u32(&arrive[rb]);
        if (offd) ainc_u32(&arrive[cb]);
        while (aload_u32(&arrive[rb]) < target) __builtin_amdgcn_s_sleep(2);
        if (offd)
            while (aload_u32(&arrive[cb]) < target) __builtin_amdgcn_s_sleep(2);
    }
    __syncthreads();

    // ---- load final gates (relaxed atomic loads, pre-margined) ----
    mpR[tid] = ord2f(aload_u32(&minp_ord[rowBase + tid])) - MARGIN;  // neg kept if s > this
    mnR[tid] = ord2f(aload_u32(&maxn_ord[rowBase + tid])) + MARGIN;  // pos kept if s < this
    if (tid < 64) {
        mpC[tid] = ord2f(aload_u32(&minp_ord[colBase + tid])) - MARGIN;
        mnC[tid] = ord2f(aload_u32(&maxn_ord[colBase + tid])) + MARGIN;
    }
    __syncthreads();

    // ---- phase 2: gated exp sums from LIVE accumulators ----
    float cps[4] = {}, cns[4] = {};
    float mpCv[4], mnCv[4];
#pragma unroll
    for (int ni = 0; ni < 4; ++ni) {
        mpCv[ni] = mpC[ni * 16 + cIn];
        mnCv[ni] = mnC[ni * 16 + cIn];
    }
#pragma unroll
    for (int mi = 0; mi < 4; ++mi)
#pragma unroll
        for (int rr = 0; rr < 4; ++rr) {
            const int rLoc = wave * 64 + mi * 16 + q * 4 + rr;
            const int rLab = rLabv[mi * 4 + rr];
            const float gateN = mpR[rLoc];
            const float gateP = mnR[rLoc];
            float rp = 0.f, rn = 0.f;
#pragma unroll
            for (int ni = 0; ni < 4; ++ni) {
                const float s = acc[mi][ni][rr];
                if (rLab == cLabv[ni]) {
                    if (s < 1.0f - EPSV) {
                        float ev = __expf(-SCALE_POS * (s - THRESH));
                        if (s < gateP) rp += ev;
                        if (offd && s < mnCv[ni]) cps[ni] += ev;
                    }
                } else {
                    float ev = __expf(SCALE_NEG * (s - THRESH));
                    if (s > gateN) rn += ev;
                    if (offd && s > mpCv[ni]) cns[ni] += ev;
                }
            }
#pragma unroll
            for (int off = 8; off; off >>= 1) {
                rp += __shfl_xor(rp, off, 16);
                rn += __shfl_xor(rn, off, 16);
            }
            if (cIn == 0) {
                if (rp != 0.f) atomicAdd(&psum[rowBase + rLoc], rp);
                if (rn != 0.f) atomicAdd(&nsum[rowBase + rLoc], rn);
            }
        }
    if (offd) {
#pragma unroll
        for (int ni = 0; ni < 4; ++ni) {
            cps[ni] += __shfl_xor(cps[ni], 16, 64);
            cps[ni] += __shfl_xor(cps[ni], 32, 64);
            cns[ni] += __shfl_xor(cns[ni], 16, 64);
            cns[ni] += __shfl_xor(cns[ni], 32, 64);
            if (q == 0) {
                const int cLoc = ni * 16 + cIn;
                if (cps[ni] != 0.f) atomicAdd(&psum[colBase + cLoc], cps[ni]);
                if (cns[ni] != 0.f) atomicAdd(&nsum[colBase + cLoc], cns[ni]);
            }
        }
    }

    // ---- last-block scalar reduction (relaxed done counter) ----
    __syncthreads();   // drains vmcnt: psum/nsum atomics complete
    if (tid == 0) {
        unsigned prev = __hip_atomic_fetch_add(done_cnt, 1u, __ATOMIC_RELAXED,
                                               __HIP_MEMORY_SCOPE_AGENT);
        lastflag = (prev == gridDim.x - 1) ? 1u : 0u;
    }
    __syncthreads();
    if (lastflag) {
        float a = 0.f;
        for (int i = tid; i < B; i += 128) {
            float pv = atomicAdd(&psum[i], 0.0f);   // coherent returning atomic
            float nv = atomicAdd(&nsum[i], 0.0f);
            if (pv > 0.f && nv > 0.f)
                a += log1pf(pv) * (1.0f / SCALE_POS) + log1pf(nv) * (1.0f / SCALE_NEG);
        }
#pragma unroll
        for (int off = 32; off; off >>= 1) a += __shfl_down(a, off, 64);
        if ((tid & 63) == 0) red[tid >> 6] = a;
        __syncthreads();
        if (tid == 0) out[0] = (red[0] + red[1]) / (float)B;
    }
}

// =====================================================================
// FALLBACK PATH — R10's proven kernels (146 us)
// =====================================================================
__global__ void __launch_bounds__(128, 2)
k_gemm_h(const unsigned short* __restrict__ fb16,
         const int* __restrict__ labels,
         unsigned* __restrict__ minp_ord,
         unsigned* __restrict__ maxn_ord,
         _Float16* __restrict__ simh,
         int D, int nb) {
    __shared__ __align__(16) unsigned short As[128 * 32];
    __shared__ __align__(16) unsigned short Bs[64 * 32];
    __shared__ int labR[128], labC[64];

    const int bid = blockIdx.x;
    int t = bid >> 1;
    const int h = bid & 1;
    int rb = 0, rem = t;
    while (rem >= nb - rb) { rem -= nb - rb; ++rb; }
    const int cb = rb + rem;
    const int rowBase = rb * 128;
    const int colBase = cb * 128 + h * 64;

    const int tid = threadIdx.x;
    const int lane = tid & 63;
    const int wave = tid >> 6;
    const int q = lane >> 4;
    const int cIn = lane & 15;

    labR[tid] = labels[rowBase + tid];
    if (tid < 64) labC[tid] = labels[colBase + tid];

    const int srow = lane >> 2;
    const int scol = (lane & 3) * 8;
    const unsigned short* gP[6];
    unsigned short* lP[6];
#pragma unroll
    for (int j = 0; j < 6; ++j) {
        const int c = wave * 6 + j;
        const int base = (c < 8) ? (rowBase + c * 16) : (colBase + (c - 8) * 16);
        gP[j] = fb16 + (size_t)(base + srow) * D + scol;
        lP[j] = ((c < 8) ? (As + c * 512) : (Bs + (c - 8) * 512)) + lane * 8;
    }

    int aOff[4], bOff[4];
#pragma unroll
    for (int i = 0; i < 4; ++i) {
        aOff[i] = (wave * 64 + i * 16 + cIn) * 32 + q * 8;
        bOff[i] = (i * 16 + cIn) * 32 + q * 8;
    }

    floatx4 acc[4][4] = {};

    const int KT = D >> 5;
    for (int kt = 0; kt < KT; ++kt) {
        const int kOff = kt * 32;
        __syncthreads();
#pragma unroll
        for (int j = 0; j < 6; ++j)
            __builtin_amdgcn_global_load_lds((gvoid*)(gP[j] + kOff), (svoid*)lP[j], 16, 0, 0);
        __syncthreads();

        short8 a[4], b[4];
#pragma unroll
        for (int i = 0; i < 4; ++i) a[i] = *(const short8*)(As + aOff[i]);
#pragma unroll
        for (int i = 0; i < 4; ++i) b[i] = *(const short8*)(Bs + bOff[i]);
#pragma unroll
        for (int i = 0; i < 4; ++i)
#pragma unroll
            for (int j = 0; j < 4; ++j)
                acc[i][j] = __builtin_amdgcn_mfma_f32_16x16x32_bf16(a[i], b[j], acc[i][j], 0, 0, 0);
    }

    int rLabv[16];
#pragma unroll
    for (int mi = 0; mi < 4; ++mi)
#pragma unroll
        for (int rr = 0; rr < 4; ++rr)
            rLabv[mi * 4 + rr] = labR[wave * 64 + mi * 16 + q * 4 + rr];
    int cLabv[4];
#pragma unroll
    for (int ni = 0; ni < 4; ++ni)
        cLabv[ni] = labC[ni * 16 + cIn];

    {
        half8* dst = (half8*)(simh + (size_t)bid * 8192 + (size_t)tid * 64);
#pragma unroll
        for (int mi = 0; mi < 4; ++mi) {
            half8 h0, h1;
#pragma unroll
            for (int ni = 0; ni < 2; ++ni)
#pragma unroll
                for (int rr = 0; rr < 4; ++rr) {
                    h0[ni * 4 + rr] = (_Float16)acc[mi][ni][rr];
                    h1[ni * 4 + rr] = (_Float16)acc[mi][ni + 2][rr];
                }
            dst[mi * 2] = h0;
            dst[mi * 2 + 1] = h1;
        }
    }

#pragma unroll
    for (int mi = 0; mi < 4; ++mi)
#pragma unroll
        for (int rr = 0; rr < 4; ++rr) {
            const int rLoc = wave * 64 + mi * 16 + q * 4 + rr;
            const int rLab = rLabv[mi * 4 + rr];
            float vmin = 1e30f, vmax = -1e30f;
#pragma unroll
            for (int ni = 0; ni < 4; ++ni) {
                float s = acc[mi][ni][rr];
                if (rLab == cLabv[ni]) {
                    if (s < 1.0f - EPSV) vmin = fminf(vmin, s);
                } else {
                    vmax = fmaxf(vmax, s);
                }
            }
#pragma unroll
            for (int off = 8; off; off >>= 1) {
                vmin = fminf(vmin, __shfl_xor(vmin, off, 16));
                vmax = fmaxf(vmax, __shfl_xor(vmax, off, 16));
            }
            if (cIn == 0) {
                if (vmin < 1e30f) atomicMin(&minp_ord[rowBase + rLoc], f2ord(vmin));
                if (vmax > -1e30f) atomicMax(&maxn_ord[rowBase + rLoc], f2ord(vmax));
            }
        }

    if (rb != cb) {
#pragma unroll
        for (int ni = 0; ni < 4; ++ni) {
            const int cLab = cLabv[ni];
            float vmin = 1e30f, vmax = -1e30f;
#pragma unroll
            for (int mi = 0; mi < 4; ++mi)
#pragma unroll
                for (int rr = 0; rr < 4; ++rr) {
                    float s = acc[mi][ni][rr];
                    if (rLabv[mi * 4 + rr] == cLab) {
                        if (s < 1.0f - EPSV) vmin = fminf(vmin, s);
                    } else {
                        vmax = fmaxf(vmax, s);
                    }
                }
            vmin = fminf(vmin, __shfl_xor(vmin, 16, 64));
            vmin = fminf(vmin, __shfl_xor(vmin, 32, 64));
            vmax = fmaxf(vmax, __shfl_xor(vmax, 16, 64));
            vmax = fmaxf(vmax, __shfl_xor(vmax, 32, 64));
            if (q == 0) {
                const int cLoc = ni * 16 + cIn;
                if (vmin < 1e30f) atomicMin(&minp_ord[colBase + cLoc], f2ord(vmin));
                if (vmax > -1e30f) atomicMax(&maxn_ord[colBase + cLoc], f2ord(vmax));
            }
        }
    }
}

__global__ void __launch_bounds__(256)
k_sum2f(const _Float16* __restrict__ simh,
        const int* __restrict__ labels,
        const unsigned* __restrict__ minp_ord,
        const unsigned* __restrict__ maxn_ord,
        float* __restrict__ psum, float* __restrict__ nsum,
        unsigned* __restrict__ done_cnt,
        float* __restrict__ out,
        int nb, int B) {
    __shared__ int labR[128], labC[128];
    __shared__ float mpR[128], mnR[128], mpC[128], mnC[128];
    __shared__ float red[4];
    __shared__ unsigned lastflag;

    int t = blockIdx.x;
    int rb = 0, rem = t;
    while (rem >= nb - rb) { rem -= nb - rb; ++rb; }
    const int cb = rb + rem;
    const int rowBase = rb * 128;

    const int tid = threadIdx.x;
    const int sub = tid >> 7;
    const int stid = tid & 127;
    const int wave = stid >> 6;
    const int lane = tid & 63;
    const int q = lane >> 4;
    const int cIn = lane & 15;
    const int colBase = cb * 128 + sub * 64;

    if (tid < 128) {
        labR[tid] = labels[rowBase + tid];
        mpR[tid] = ord2f(minp_ord[rowBase + tid]) - MARGIN;
        mnR[tid] = ord2f(maxn_ord[rowBase + tid]) + MARGIN;
    } else {
        const int j = tid - 128;
        labC[j] = labels[cb * 128 + j];
        mpC[j] = ord2f(minp_ord[cb * 128 + j]) - MARGIN;
        mnC[j] = ord2f(maxn_ord[cb * 128 + j]) + MARGIN;
    }
    __syncthreads();

    int cLabv[4];
    float mpCv[4], mnCv[4];
#pragma unroll
    for (int ni = 0; ni < 4; ++ni) {
        const int j = sub * 64 + ni * 16 + cIn;
        cLabv[ni] = labC[j];
        mpCv[ni] = mpC[j];
        mnCv[ni] = mnC[j];
    }

    const half8* src = (const half8*)(simh + (size_t)(2 * t + sub) * 8192 + (size_t)stid * 64);
    half8 hv[8];
#pragma unroll
    for (int v = 0; v < 8; ++v) hv[v] = src[v];

    float cps[4] = {}, cns[4] = {};
    const bool offd = (rb != cb);

#pragma unroll
    for (int mi = 0; mi < 4; ++mi)
#pragma unroll
        for (int rr = 0; rr < 4; ++rr) {
            const int rLoc = wave * 64 + mi * 16 + q * 4 + rr;
            const int rLab = labR[rLoc];
            const float gateN = mpR[rLoc];
            const float gateP = mnR[rLoc];
            float rp = 0.f, rn = 0.f;
#pragma unroll
            for (int ni = 0; ni < 4; ++ni) {
                const int idx = mi * 16 + ni * 4 + rr;
                const float s = (float)hv[idx >> 3][idx & 7];
                if (rLab == cLabv[ni]) {
                    if (s < 1.0f - EPSV) {
                        float ev = __expf(-SCALE_POS * (s - THRESH));
                        if (s < gateP) rp += ev;
                        if (offd && s < mnCv[ni]) cps[ni] += ev;
                    }
                } else {
                    float ev = __expf(SCALE_NEG * (s - THRESH));
                    if (s > gateN) rn += ev;
                    if (offd && s > mpCv[ni]) cns[ni] += ev;
                }
            }
#pragma unroll
            for (int off = 8; off; off >>= 1) {
                rp += __shfl_xor(rp, off, 16);
                rn += __shfl_xor(rn, off, 16);
            }
            if (cIn == 0) {
                if (rp != 0.f) atomicAdd(&psum[rowBase + rLoc], rp);
                if (rn != 0.f) atomicAdd(&nsum[rowBase + rLoc], rn);
            }
        }
    if (offd) {
#pragma unroll
        for (int ni = 0; ni < 4; ++ni) {
            cps[ni] += __shfl_xor(cps[ni], 16, 64);
            cps[ni] += __shfl_xor(cps[ni], 32, 64);
            cns[ni] += __shfl_xor(cns[ni], 16, 64);
            cns[ni] += __shfl_xor(cns[ni], 32, 64);
            if (q == 0) {
                const int cLoc = ni * 16 + cIn;
                if (cps[ni] != 0.f) atomicAdd(&psum[colBase + cLoc], cps[ni]);
                if (cns[ni] != 0.f) atomicAdd(&nsum[colBase + cLoc], cns[ni]);
            }
        }
    }

    __syncthreads();
    if (tid == 0) {
        unsigned prev = __hip_atomic_fetch_add(done_cnt, 1u, __ATOMIC_RELAXED,
                                               __HIP_MEMORY_SCOPE_AGENT);
        lastflag = (prev == (unsigned)(gridDim.x - 1)) ? 1u : 0u;
    }
    __syncthreads();
    if (lastflag) {
        float a = 0.f;
        for (int i = tid; i < B; i += 256) {
            float pv = atomicAdd(&psum[i], 0.0f);
            float nv = atomicAdd(&nsum[i], 0.0f);
            if (pv > 0.f && nv > 0.f)
                a += log1pf(pv) * (1.0f / SCALE_POS) + log1pf(nv) * (1.0f / SCALE_NEG);
        }
#pragma unroll
        for (int off = 32; off; off >>= 1) a += __shfl_down(a, off, 64);
        if ((tid & 63) == 0) red[tid >> 6] = a;
        __syncthreads();
        if (tid == 0) out[0] = (red[0] + red[1] + red[2] + red[3]) / (float)B;
    }
}

extern "C" void kernel_launch(void* const* d_in, const int* in_sizes, int n_in,
                              void* d_out, int out_size, void* d_ws, size_t ws_size,
                              hipStream_t stream) {
    const float* feats = (const float*)d_in[0];
    const int* labels = (const int*)d_in[1];
    int B = in_sizes[1];                  // 4096
    int D = in_sizes[0] / B;              // 1024
    int nb = B / 128;                     // 32
    const int NT = nb * (nb + 1) / 2;     // 528
    const int NH = NT * 2;                // 1056 half-tiles
    int total4 = B * D / 4;

    char* ws = (char*)d_ws;
    unsigned short* fb16 = (unsigned short*)ws;
    size_t off = (size_t)B * D * sizeof(unsigned short);
    unsigned* minp = (unsigned*)(ws + off); off += (size_t)B * 4;
    unsigned* maxn = (unsigned*)(ws + off); off += (size_t)B * 4;
    float* psum = (float*)(ws + off); off += (size_t)B * 4;
    float* nsum = (float*)(ws + off); off += (size_t)B * 4;
    unsigned* cnts = (unsigned*)(ws + off); off += 256;   // zeroed by k_init
    _Float16* simh = (_Float16*)(ws + ((off + 255) & ~(size_t)255));
    float* outp = (float*)d_out;

    k_init<<<(total4 + 255) / 256, 256, 0, stream>>>(feats, fb16, minp, maxn,
                                                     psum, nsum, cnts, total4, B);

    // ---- primary: fused kernel, cooperative launch for co-residency ----
    unsigned* arrive = cnts;          // arrive[0..nb-1]
    unsigned* done0 = cnts + 32;
    void* kargs[] = {
        (void*)&fb16, (void*)&labels, (void*)&minp, (void*)&maxn,
        (void*)&psum, (void*)&nsum, (void*)&arrive, (void*)&done0,
        (void*)&outp, (void*)&D, (void*)&nb, (void*)&B
    };
    hipError_t err = hipLaunchCooperativeKernel((const void*)(uintptr_t)&k_fused,
                                                dim3(NH), dim3(128), kargs, 0, stream);
    if (err == hipSuccess) return;
    (void)hipGetLastError();  // clear error; fall back

    // ---- fallback: R10's proven 3-kernel path ----
    k_gemm_h<<<NH, 128, 0, stream>>>(fb16, labels, minp, maxn, simh, D, nb);
    k_sum2f<<<NT, 256, 0, stream>>>(simh, labels, minp, maxn, psum, nsum,
                                    &cnts[33], outp, nb, B);
}

// Round 12
// 204.566 us; speedup vs baseline: 1.2420x; 1.2420x over previous
//
#include <hip/hip_runtime.h>

typedef short short8 __attribute__((ext_vector_type(8)));
typedef _Float16 half8 __attribute__((ext_vector_type(8)));
typedef float floatx4 __attribute__((ext_vector_type(4)));
typedef __attribute__((address_space(1))) const void gvoid;
typedef __attribute__((address_space(3))) void svoid;

#define SCALE_POS 2.0f
#define SCALE_NEG 40.0f
#define THRESH 0.5f
#define MARGIN 0.1f
#define EPSV 1e-5f

__device__ __forceinline__ unsigned short f2bf(float f) {
    unsigned u = __float_as_uint(f);
    u += 0x7fffu + ((u >> 16) & 1u);   // round-to-nearest-even
    return (unsigned short)(u >> 16);
}
// order-preserving float<->uint map (no NaNs present)
__device__ __forceinline__ unsigned f2ord(float f) {
    unsigned u = __float_as_uint(f);
    return (u & 0x80000000u) ? ~u : (u | 0x80000000u);
}
__device__ __forceinline__ float ord2f(unsigned e) {
    unsigned v = (e & 0x80000000u) ? (e & 0x7fffffffu) : ~e;
    return __uint_as_float(v);
}

#define ORD_POS_INF 0xff800000u   // f2ord(+inf)
#define ORD_NEG_INF 0x007fffffu   // f2ord(-inf)

// ---- kernel 1: fp32 -> bf16 cast + stat/counter init ----
__global__ void k_init(const float* __restrict__ feats,
                       unsigned short* __restrict__ fb16,
                       unsigned* __restrict__ minp, unsigned* __restrict__ maxn,
                       float* __restrict__ psum, float* __restrict__ nsum,
                       unsigned* __restrict__ cnts,
                       int total4, int B) {
    int i = blockIdx.x * blockDim.x + threadIdx.x;
    if (i < total4) {
        float4 v = ((const float4*)feats)[i];
        ushort4 o;
        o.x = f2bf(v.x); o.y = f2bf(v.y); o.z = f2bf(v.z); o.w = f2bf(v.w);
        ((ushort4*)fb16)[i] = o;
    }
    if (i < B) {
        minp[i] = ORD_POS_INF;
        maxn[i] = ORD_NEG_INF;
        psum[i] = 0.f;
        nsum[i] = 0.f;
    }
    if (i < 64) cnts[i] = 0;   // [1] = sum2f done counter
}

// =====================================================================
// kernel 2: WAVE-SYNCHRONOUS symmetric GEMM over 64x64 quarter-tiles.
// 2080 upper-tri (rb<=cb at 64-granularity) blocks, ONE WAVE each.
// The wave computes the full 64x64 output (4x4 MFMA tiles/iter) with
// ZERO __syncthreads: global_load_lds x8 -> s_waitcnt(0) -> ds_read ->
// MFMA. No barrier drain (the structural stall of every 50-57us variant);
// 8.125 waves/CU (tail 1.6% vs 50%). Staging bytes 2x (L2/L3-resident).
// Diagonal quarters: row stats only. Off-diag: row + col (symmetry).
// fp16 store for pass 2.
// =====================================================================
__global__ void __launch_bounds__(64)
k_gemm_q(const unsigned short* __restrict__ fb16,
         const int* __restrict__ labels,
         unsigned* __restrict__ minp_ord,
         unsigned* __restrict__ maxn_ord,
         _Float16* __restrict__ simh,
         int D, int n64) {
    __shared__ __align__(16) unsigned short As[64 * 32];  // 4 KB
    __shared__ __align__(16) unsigned short Bs[64 * 32];  // 4 KB

    const int bid = blockIdx.x;
    int rb = 0, rem = bid;
    while (rem >= n64 - rb) { rem -= n64 - rb; ++rb; }
    const int cb = rb + rem;
    const int rowBase = rb * 64;
    const int colBase = cb * 64;
    const bool offd = (rb != cb);

    const int lane = threadIdx.x;   // 0..63, single wave
    const int q = lane >> 4;
    const int cIn = lane & 15;
    const int srow = lane >> 2;
    const int scol = (lane & 3) * 8;

    // staging: 4 chunks (16 rows x 32 cols = 1KB) per operand
    const unsigned short* gA[4];
    const unsigned short* gB[4];
    unsigned short *lA[4], *lB[4];
#pragma unroll
    for (int j = 0; j < 4; ++j) {
        gA[j] = fb16 + (size_t)(rowBase + j * 16 + srow) * D + scol;
        gB[j] = fb16 + (size_t)(colBase + j * 16 + srow) * D + scol;
        lA[j] = As + j * 512 + lane * 8;
        lB[j] = Bs + j * 512 + lane * 8;
    }

    int abOff[4];
#pragma unroll
    for (int i = 0; i < 4; ++i) abOff[i] = (i * 16 + cIn) * 32 + q * 8;

    floatx4 acc[4][4] = {};

    const int KT = D >> 5;
    for (int kt = 0; kt < KT; ++kt) {
        const int kOff = kt * 32;
#pragma unroll
        for (int j = 0; j < 4; ++j)
            __builtin_amdgcn_global_load_lds((gvoid*)(gA[j] + kOff), (svoid*)lA[j], 16, 0, 0);
#pragma unroll
        for (int j = 0; j < 4; ++j)
            __builtin_amdgcn_global_load_lds((gvoid*)(gB[j] + kOff), (svoid*)lB[j], 16, 0, 0);
        __builtin_amdgcn_s_waitcnt(0);   // wave-private LDS now ready; no barrier needed

        short8 a[4], b[4];
#pragma unroll
        for (int i = 0; i < 4; ++i) a[i] = *(const short8*)(As + abOff[i]);
#pragma unroll
        for (int i = 0; i < 4; ++i) b[i] = *(const short8*)(Bs + abOff[i]);
#pragma unroll
        for (int i = 0; i < 4; ++i)
#pragma unroll
            for (int j = 0; j < 4; ++j)
                acc[i][j] = __builtin_amdgcn_mfma_f32_16x16x32_bf16(a[i], b[j], acc[i][j], 0, 0, 0);
    }

    // labels direct from global (L2-hit; avoids LDS arrays in a 1-wave block)
    int rLabv[16];
#pragma unroll
    for (int mi = 0; mi < 4; ++mi)
#pragma unroll
        for (int rr = 0; rr < 4; ++rr)
            rLabv[mi * 4 + rr] = labels[rowBase + mi * 16 + q * 4 + rr];
    int cLabv[4];
#pragma unroll
    for (int ni = 0; ni < 4; ++ni)
        cLabv[ni] = labels[colBase + ni * 16 + cIn];

    // ---- fp16 store: thread-major, 64 contiguous halves ----
    {
        half8* dst = (half8*)(simh + (size_t)bid * 4096 + (size_t)lane * 64);
#pragma unroll
        for (int mi = 0; mi < 4; ++mi) {
            half8 h0, h1;
#pragma unroll
            for (int ni = 0; ni < 2; ++ni)
#pragma unroll
                for (int rr = 0; rr < 4; ++rr) {
                    h0[ni * 4 + rr] = (_Float16)acc[mi][ni][rr];
                    h1[ni * 4 + rr] = (_Float16)acc[mi][ni + 2][rr];
                }
            dst[mi * 2] = h0;
            dst[mi * 2 + 1] = h1;
        }
    }

    // ---- row stats ----
#pragma unroll
    for (int mi = 0; mi < 4; ++mi)
#pragma unroll
        for (int rr = 0; rr < 4; ++rr) {
            const int rLoc = mi * 16 + q * 4 + rr;
            const int rLab = rLabv[mi * 4 + rr];
            float vmin = 1e30f, vmax = -1e30f;
#pragma unroll
            for (int ni = 0; ni < 4; ++ni) {
                float s = acc[mi][ni][rr];
                if (rLab == cLabv[ni]) {
                    if (s < 1.0f - EPSV) vmin = fminf(vmin, s);
                } else {
                    vmax = fmaxf(vmax, s);
                }
            }
#pragma unroll
            for (int off = 8; off; off >>= 1) {
                vmin = fminf(vmin, __shfl_xor(vmin, off, 16));
                vmax = fmaxf(vmax, __shfl_xor(vmax, off, 16));
            }
            if (cIn == 0) {
                if (vmin < 1e30f) atomicMin(&minp_ord[rowBase + rLoc], f2ord(vmin));
                if (vmax > -1e30f) atomicMax(&maxn_ord[rowBase + rLoc], f2ord(vmax));
            }
        }

    // ---- col stats via symmetry (off-diagonal quarters only) ----
    if (offd) {
#pragma unroll
        for (int ni = 0; ni < 4; ++ni) {
            const int cLab = cLabv[ni];
            float vmin = 1e30f, vmax = -1e30f;
#pragma unroll
            for (int mi = 0; mi < 4; ++mi)
#pragma unroll
                for (int rr = 0; rr < 4; ++rr) {
                    float s = acc[mi][ni][rr];
                    if (rLabv[mi * 4 + rr] == cLab) {
                        if (s < 1.0f - EPSV) vmin = fminf(vmin, s);
                    } else {
                        vmax = fmaxf(vmax, s);
                    }
                }
            vmin = fminf(vmin, __shfl_xor(vmin, 16, 64));
            vmin = fminf(vmin, __shfl_xor(vmin, 32, 64));
            vmax = fmaxf(vmax, __shfl_xor(vmax, 16, 64));
            vmax = fmaxf(vmax, __shfl_xor(vmax, 32, 64));
            if (q == 0) {
                const int cLoc = ni * 16 + cIn;
                if (vmin < 1e30f) atomicMin(&minp_ord[colBase + cLoc], f2ord(vmin));
                if (vmax > -1e30f) atomicMax(&maxn_ord[colBase + cLoc], f2ord(vmax));
            }
        }
    }
}

// =====================================================================
// kernel 3: pass 2 over quarter-tiles (2080 blocks x 64 thr, layout
// matches the fp16 store) + fused last-block scalar reduction (RELAXED
// done counter — R10's lesson: ACQ_REL agent RMWs serialize ~55ns each).
// =====================================================================
__global__ void __launch_bounds__(64)
k_sum2f(const _Float16* __restrict__ simh,
        const int* __restrict__ labels,
        const unsigned* __restrict__ minp_ord,
        const unsigned* __restrict__ maxn_ord,
        float* __restrict__ psum, float* __restrict__ nsum,
        unsigned* __restrict__ done_cnt,
        float* __restrict__ out,
        int n64, int B) {
    __shared__ int labR[64], labC[64];
    __shared__ float mpR[64], mnR[64], mpC[64], mnC[64];
    __shared__ unsigned lastflag;

    const int bid = blockIdx.x;
    int rb = 0, rem = bid;
    while (rem >= n64 - rb) { rem -= n64 - rb; ++rb; }
    const int cb = rb + rem;
    const int rowBase = rb * 64;
    const int colBase = cb * 64;
    const bool offd = (rb != cb);

    const int lane = threadIdx.x;
    const int q = lane >> 4;
    const int cIn = lane & 15;

    labR[lane] = labels[rowBase + lane];
    mpR[lane] = ord2f(minp_ord[rowBase + lane]) - MARGIN;   // neg kept if s > this
    mnR[lane] = ord2f(maxn_ord[rowBase + lane]) + MARGIN;   // pos kept if s < this
    labC[lane] = labels[colBase + lane];
    mpC[lane] = ord2f(minp_ord[colBase + lane]) - MARGIN;
    mnC[lane] = ord2f(maxn_ord[colBase + lane]) + MARGIN;
    __syncthreads();   // single wave: cheap; orders LDS writes before reads

    int cLabv[4];
    float mpCv[4], mnCv[4];
#pragma unroll
    for (int ni = 0; ni < 4; ++ni) {
        const int cLoc = ni * 16 + cIn;
        cLabv[ni] = labC[cLoc];
        mpCv[ni] = mpC[cLoc];
        mnCv[ni] = mnC[cLoc];
    }

    const half8* src = (const half8*)(simh + (size_t)bid * 4096 + (size_t)lane * 64);
    half8 hv[8];
#pragma unroll
    for (int v = 0; v < 8; ++v) hv[v] = src[v];

    float cps[4] = {}, cns[4] = {};

#pragma unroll
    for (int mi = 0; mi < 4; ++mi)
#pragma unroll
        for (int rr = 0; rr < 4; ++rr) {
            const int rLoc = mi * 16 + q * 4 + rr;
            const int rLab = labR[rLoc];
            const float gateN = mpR[rLoc];
            const float gateP = mnR[rLoc];
            float rp = 0.f, rn = 0.f;
#pragma unroll
            for (int ni = 0; ni < 4; ++ni) {
                const int idx = mi * 16 + ni * 4 + rr;
                const float s = (float)hv[idx >> 3][idx & 7];
                if (rLab == cLabv[ni]) {
                    if (s < 1.0f - EPSV) {
                        float ev = __expf(-SCALE_POS * (s - THRESH));
                        if (s < gateP) rp += ev;
                        if (offd && s < mnCv[ni]) cps[ni] += ev;
                    }
                } else {
                    float ev = __expf(SCALE_NEG * (s - THRESH));
                    if (s > gateN) rn += ev;
                    if (offd && s > mpCv[ni]) cns[ni] += ev;
                }
            }
#pragma unroll
            for (int off = 8; off; off >>= 1) {
                rp += __shfl_xor(rp, off, 16);
                rn += __shfl_xor(rn, off, 16);
            }
            if (cIn == 0) {
                if (rp != 0.f) atomicAdd(&psum[rowBase + rLoc], rp);
                if (rn != 0.f) atomicAdd(&nsum[rowBase + rLoc], rn);
            }
        }
    if (offd) {
#pragma unroll
        for (int ni = 0; ni < 4; ++ni) {
            cps[ni] += __shfl_xor(cps[ni], 16, 64);
            cps[ni] += __shfl_xor(cps[ni], 32, 64);
            cns[ni] += __shfl_xor(cns[ni], 16, 64);
            cns[ni] += __shfl_xor(cns[ni], 32, 64);
            if (q == 0) {
                const int cLoc = ni * 16 + cIn;
                if (cps[ni] != 0.f) atomicAdd(&psum[colBase + cLoc], cps[ni]);
                if (cns[ni] != 0.f) atomicAdd(&nsum[colBase + cLoc], cns[ni]);
            }
        }
    }

    // ---- last-block final reduction (relaxed counter, no fences) ----
    // __syncthreads() drains vmcnt -> this block's psum/nsum atomics are
    // complete at the coherence point before the increment below.
    __syncthreads();
    if (lane == 0) {
        unsigned prev = __hip_atomic_fetch_add(done_cnt, 1u, __ATOMIC_RELAXED,
                                               __HIP_MEMORY_SCOPE_AGENT);
        lastflag = (prev == (unsigned)(gridDim.x - 1)) ? 1u : 0u;
    }
    __syncthreads();
    if (lastflag) {
        float a = 0.f;
        for (int i = lane; i < B; i += 64) {
            float pv = atomicAdd(&psum[i], 0.0f);   // coherent returning atomic
            float nv = atomicAdd(&nsum[i], 0.0f);
            if (pv > 0.f && nv > 0.f)
                a += log1pf(pv) * (1.0f / SCALE_POS) + log1pf(nv) * (1.0f / SCALE_NEG);
        }
#pragma unroll
        for (int off = 32; off; off >>= 1) a += __shfl_down(a, off, 64);
        if (lane == 0) out[0] = a / (float)B;
    }
}

extern "C" void kernel_launch(void* const* d_in, const int* in_sizes, int n_in,
                              void* d_out, int out_size, void* d_ws, size_t ws_size,
                              hipStream_t stream) {
    const float* feats = (const float*)d_in[0];
    const int* labels = (const int*)d_in[1];
    const int B = in_sizes[1];            // 4096
    const int D = in_sizes[0] / B;        // 1024
    const int n64 = B / 64;               // 64
    const int NQ = n64 * (n64 + 1) / 2;   // 2080 quarter-tiles
    const int total4 = B * D / 4;

    char* ws = (char*)d_ws;
    unsigned short* fb16 = (unsigned short*)ws;
    size_t off = (size_t)B * D * sizeof(unsigned short);
    unsigned* minp = (unsigned*)(ws + off); off += (size_t)B * 4;
    unsigned* maxn = (unsigned*)(ws + off); off += (size_t)B * 4;
    float* psum = (float*)(ws + off); off += (size_t)B * 4;
    float* nsum = (float*)(ws + off); off += (size_t)B * 4;
    unsigned* cnts = (unsigned*)(ws + off); off += 256;   // zeroed by k_init
    _Float16* simh = (_Float16*)(ws + ((off + 255) & ~(size_t)255));
    float* outp = (float*)d_out;

    k_init<<<(total4 + 255) / 256, 256, 0, stream>>>(feats, fb16, minp, maxn,
                                                     psum, nsum, cnts, total4, B);

    // 2080 single-wave blocks: barrier-free K-loop, 8.125 waves/CU
    k_gemm_q<<<NQ, 64, 0, stream>>>(fb16, labels, minp, maxn, simh, D, n64);

    k_sum2f<<<NQ, 64, 0, stream>>>(simh, labels, minp, maxn, psum, nsum,
                                   &cnts[1], outp, n64, B);
}

// Round 13
// 144.186 us; speedup vs baseline: 1.7622x; 1.4188x over previous
//
#include <hip/hip_runtime.h>

typedef short short8 __attribute__((ext_vector_type(8)));
typedef _Float16 half8 __attribute__((ext_vector_type(8)));
typedef float floatx4 __attribute__((ext_vector_type(4)));
typedef __attribute__((address_space(1))) const void gvoid;
typedef __attribute__((address_space(3))) void svoid;

#define SCALE_POS 2.0f
#define SCALE_NEG 40.0f
#define THRESH 0.5f
#define MARGIN 0.1f
#define EPSV 1e-5f

__device__ __forceinline__ unsigned short f2bf(float f) {
    unsigned u = __float_as_uint(f);
    u += 0x7fffu + ((u >> 16) & 1u);   // round-to-nearest-even
    return (unsigned short)(u >> 16);
}
// order-preserving float<->uint map (no NaNs present)
__device__ __forceinline__ unsigned f2ord(float f) {
    unsigned u = __float_as_uint(f);
    return (u & 0x80000000u) ? ~u : (u | 0x80000000u);
}
__device__ __forceinline__ float ord2f(unsigned e) {
    unsigned v = (e & 0x80000000u) ? (e & 0x7fffffffu) : ~e;
    return __uint_as_float(v);
}

#define ORD_POS_INF 0xff800000u   // f2ord(+inf)
#define ORD_NEG_INF 0x007fffffu   // f2ord(-inf)

// ---- kernel 1: fp32 -> bf16 cast + stat/counter init ----
__global__ void k_init(const float* __restrict__ feats,
                       unsigned short* __restrict__ fb16,
                       unsigned* __restrict__ minp, unsigned* __restrict__ maxn,
                       float* __restrict__ psum, float* __restrict__ nsum,
                       unsigned* __restrict__ cnts,
                       int total4, int B) {
    int i = blockIdx.x * blockDim.x + threadIdx.x;
    if (i < total4) {
        float4 v = ((const float4*)feats)[i];
        ushort4 o;
        o.x = f2bf(v.x); o.y = f2bf(v.y); o.z = f2bf(v.z); o.w = f2bf(v.w);
        ((ushort4*)fb16)[i] = o;
    }
    if (i < B) {
        minp[i] = ORD_POS_INF;
        maxn[i] = ORD_NEG_INF;
        psum[i] = 0.f;
        nsum[i] = 0.f;
    }
    if (i < 2048) cnts[i] = 0;   // top @0; stripe s @ (1+s)*32 (128B apart)
}

// =====================================================================
// kernel 2 (R10's proven GEMM, unchanged): symmetric GEMM over 128x64
// HALF-tiles. 1056 blocks x 128 thr (2 waves, each a full 64x64 worker,
// 16 MFMA/wave/iter). Diagonal halves: row stats only. Off-diag:
// row + col (symmetry) stats. fp16 tile store for pass 2.
// Structural plateau: ~54us = ~350 TF, the m97-structure at K=1024
// (verified from 6 directions: R2/R5/R7/R8/R9/R12 all 50-57us).
// =====================================================================
__global__ void __launch_bounds__(128, 2)
k_gemm_h(const unsigned short* __restrict__ fb16,
         const int* __restrict__ labels,
         unsigned* __restrict__ minp_ord,
         unsigned* __restrict__ maxn_ord,
         _Float16* __restrict__ simh,
         int D, int nb) {
    __shared__ __align__(16) unsigned short As[128 * 32];  // 8 KB
    __shared__ __align__(16) unsigned short Bs[64 * 32];   // 4 KB
    __shared__ int labR[128], labC[64];

    const int bid = blockIdx.x;
    int t = bid >> 1;
    const int h = bid & 1;
    int rb = 0, rem = t;
    while (rem >= nb - rb) { rem -= nb - rb; ++rb; }
    const int cb = rb + rem;
    const int rowBase = rb * 128;
    const int colBase = cb * 128 + h * 64;

    const int tid = threadIdx.x;        // 0..127
    const int lane = tid & 63;
    const int wave = tid >> 6;          // 0..1 : row half (64 rows each)
    const int q = lane >> 4;
    const int cIn = lane & 15;

    labR[tid] = labels[rowBase + tid];
    if (tid < 64) labC[tid] = labels[colBase + tid];

    // staging: 12 chunks of 1KB (16 rows x 32 cols). Wave handles 6.
    const int srow = lane >> 2;
    const int scol = (lane & 3) * 8;
    const unsigned short* gP[6];
    unsigned short* lP[6];
#pragma unroll
    for (int j = 0; j < 6; ++j) {
        const int c = wave * 6 + j;
        const int base = (c < 8) ? (rowBase + c * 16) : (colBase + (c - 8) * 16);
        gP[j] = fb16 + (size_t)(base + srow) * D + scol;
        lP[j] = ((c < 8) ? (As + c * 512) : (Bs + (c - 8) * 512)) + lane * 8;
    }

    int aOff[4], bOff[4];
#pragma unroll
    for (int i = 0; i < 4; ++i) {
        aOff[i] = (wave * 64 + i * 16 + cIn) * 32 + q * 8;
        bOff[i] = (i * 16 + cIn) * 32 + q * 8;
    }

    floatx4 acc[4][4] = {};

    const int KT = D >> 5;
    for (int kt = 0; kt < KT; ++kt) {
        const int kOff = kt * 32;
        __syncthreads();
#pragma unroll
        for (int j = 0; j < 6; ++j)
            __builtin_amdgcn_global_load_lds((gvoid*)(gP[j] + kOff), (svoid*)lP[j], 16, 0, 0);
        __syncthreads();

        short8 a[4], b[4];
#pragma unroll
        for (int i = 0; i < 4; ++i) a[i] = *(const short8*)(As + aOff[i]);
#pragma unroll
        for (int i = 0; i < 4; ++i) b[i] = *(const short8*)(Bs + bOff[i]);
#pragma unroll
        for (int i = 0; i < 4; ++i)
#pragma unroll
            for (int j = 0; j < 4; ++j)
                acc[i][j] = __builtin_amdgcn_mfma_f32_16x16x32_bf16(a[i], b[j], acc[i][j], 0, 0, 0);
    }

    int rLabv[16];
#pragma unroll
    for (int mi = 0; mi < 4; ++mi)
#pragma unroll
        for (int rr = 0; rr < 4; ++rr)
            rLabv[mi * 4 + rr] = labR[wave * 64 + mi * 16 + q * 4 + rr];
    int cLabv[4];
#pragma unroll
    for (int ni = 0; ni < 4; ++ni)
        cLabv[ni] = labC[ni * 16 + cIn];

    // ---- fp16 store: thread-major, 64 contiguous halves ----
    {
        half8* dst = (half8*)(simh + (size_t)bid * 8192 + (size_t)tid * 64);
#pragma unroll
        for (int mi = 0; mi < 4; ++mi) {
            half8 h0, h1;
#pragma unroll
            for (int ni = 0; ni < 2; ++ni)
#pragma unroll
                for (int rr = 0; rr < 4; ++rr) {
                    h0[ni * 4 + rr] = (_Float16)acc[mi][ni][rr];
                    h1[ni * 4 + rr] = (_Float16)acc[mi][ni + 2][rr];
                }
            dst[mi * 2] = h0;
            dst[mi * 2 + 1] = h1;
        }
    }

    // ---- row stats ----
#pragma unroll
    for (int mi = 0; mi < 4; ++mi)
#pragma unroll
        for (int rr = 0; rr < 4; ++rr) {
            const int rLoc = wave * 64 + mi * 16 + q * 4 + rr;
            const int rLab = rLabv[mi * 4 + rr];
            float vmin = 1e30f, vmax = -1e30f;
#pragma unroll
            for (int ni = 0; ni < 4; ++ni) {
                float s = acc[mi][ni][rr];
                if (rLab == cLabv[ni]) {
                    if (s < 1.0f - EPSV) vmin = fminf(vmin, s);
                } else {
                    vmax = fmaxf(vmax, s);
                }
            }
#pragma unroll
            for (int off = 8; off; off >>= 1) {
                vmin = fminf(vmin, __shfl_xor(vmin, off, 16));
                vmax = fmaxf(vmax, __shfl_xor(vmax, off, 16));
            }
            if (cIn == 0) {
                if (vmin < 1e30f) atomicMin(&minp_ord[rowBase + rLoc], f2ord(vmin));
                if (vmax > -1e30f) atomicMax(&maxn_ord[rowBase + rLoc], f2ord(vmax));
            }
        }

    // ---- col stats via symmetry (off-diagonal tiles only) ----
    if (rb != cb) {
#pragma unroll
        for (int ni = 0; ni < 4; ++ni) {
            const int cLab = cLabv[ni];
            float vmin = 1e30f, vmax = -1e30f;
#pragma unroll
            for (int mi = 0; mi < 4; ++mi)
#pragma unroll
                for (int rr = 0; rr < 4; ++rr) {
                    float s = acc[mi][ni][rr];
                    if (rLabv[mi * 4 + rr] == cLab) {
                        if (s < 1.0f - EPSV) vmin = fminf(vmin, s);
                    } else {
                        vmax = fmaxf(vmax, s);
                    }
                }
            vmin = fminf(vmin, __shfl_xor(vmin, 16, 64));
            vmin = fminf(vmin, __shfl_xor(vmin, 32, 64));
            vmax = fmaxf(vmax, __shfl_xor(vmax, 16, 64));
            vmax = fmaxf(vmax, __shfl_xor(vmax, 32, 64));
            if (q == 0) {
                const int cLoc = ni * 16 + cIn;
                if (vmin < 1e30f) atomicMin(&minp_ord[colBase + cLoc], f2ord(vmin));
                if (vmax > -1e30f) atomicMax(&maxn_ord[colBase + cLoc], f2ord(vmax));
            }
        }
    }
}

// =====================================================================
// kernel 3: pass 2, 528 blocks x 256 threads (R10 shape) + fused final
// reduction behind a HIERARCHICAL done-counter:
//   level 0: 32 stripe counters, 128B apart (blockIdx&31) — ~17 RMWs per
//            line in parallel across lines (~0.7us)
//   level 1: one top counter, 32 RMWs (~1.3us)
// vs R10's single counter: 528 serialized RMWs x ~40ns = 21us (R12 law).
// =====================================================================
__global__ void __launch_bounds__(256)
k_sum2f(const _Float16* __restrict__ simh,
        const int* __restrict__ labels,
        const unsigned* __restrict__ minp_ord,
        const unsigned* __restrict__ maxn_ord,
        float* __restrict__ psum, float* __restrict__ nsum,
        unsigned* __restrict__ cnts,   // top @0; stripe s @ (1+s)*32
        float* __restrict__ out,
        int nb, int B, int NT) {
    __shared__ int labR[128], labC[128];
    __shared__ float mpR[128], mnR[128], mpC[128], mnC[128];
    __shared__ float red[4];
    __shared__ unsigned lastflag;

    int t = blockIdx.x;
    int rb = 0, rem = t;
    while (rem >= nb - rb) { rem -= nb - rb; ++rb; }
    const int cb = rb + rem;
    const int rowBase = rb * 128;

    const int tid = threadIdx.x;
    const int sub = tid >> 7;           // which 64-col half of the tile
    const int stid = tid & 127;
    const int wave = stid >> 6;         // row half within half-tile
    const int lane = tid & 63;
    const int q = lane >> 4;
    const int cIn = lane & 15;
    const int colBase = cb * 128 + sub * 64;

    if (tid < 128) {
        labR[tid] = labels[rowBase + tid];
        mpR[tid] = ord2f(minp_ord[rowBase + tid]) - MARGIN;   // neg kept if s > this
        mnR[tid] = ord2f(maxn_ord[rowBase + tid]) + MARGIN;   // pos kept if s < this
    } else {
        const int j = tid - 128;        // 0..127 over both halves' columns
        labC[j] = labels[cb * 128 + j];
        mpC[j] = ord2f(minp_ord[cb * 128 + j]) - MARGIN;
        mnC[j] = ord2f(maxn_ord[cb * 128 + j]) + MARGIN;
    }
    __syncthreads();

    int cLabv[4];
    float mpCv[4], mnCv[4];
#pragma unroll
    for (int ni = 0; ni < 4; ++ni) {
        const int j = sub * 64 + ni * 16 + cIn;
        cLabv[ni] = labC[j];
        mpCv[ni] = mpC[j];
        mnCv[ni] = mnC[j];
    }

    const half8* src = (const half8*)(simh + (size_t)(2 * t + sub) * 8192 + (size_t)stid * 64);
    half8 hv[8];
#pragma unroll
    for (int v = 0; v < 8; ++v) hv[v] = src[v];

    float cps[4] = {}, cns[4] = {};
    const bool offd = (rb != cb);

#pragma unroll
    for (int mi = 0; mi < 4; ++mi)
#pragma unroll
        for (int rr = 0; rr < 4; ++rr) {
            const int rLoc = wave * 64 + mi * 16 + q * 4 + rr;
            const int rLab = labR[rLoc];
            const float gateN = mpR[rLoc];
            const float gateP = mnR[rLoc];
            float rp = 0.f, rn = 0.f;
#pragma unroll
            for (int ni = 0; ni < 4; ++ni) {
                const int idx = mi * 16 + ni * 4 + rr;
                const float s = (float)hv[idx >> 3][idx & 7];
                if (rLab == cLabv[ni]) {
                    if (s < 1.0f - EPSV) {
                        float ev = __expf(-SCALE_POS * (s - THRESH));
                        if (s < gateP) rp += ev;
                        if (offd && s < mnCv[ni]) cps[ni] += ev;
                    }
                } else {
                    float ev = __expf(SCALE_NEG * (s - THRESH));
                    if (s > gateN) rn += ev;
                    if (offd && s > mpCv[ni]) cns[ni] += ev;
                }
            }
#pragma unroll
            for (int off = 8; off; off >>= 1) {
                rp += __shfl_xor(rp, off, 16);
                rn += __shfl_xor(rn, off, 16);
            }
            if (cIn == 0) {
                if (rp != 0.f) atomicAdd(&psum[rowBase + rLoc], rp);
                if (rn != 0.f) atomicAdd(&nsum[rowBase + rLoc], rn);
            }
        }
    if (offd) {
#pragma unroll
        for (int ni = 0; ni < 4; ++ni) {
            cps[ni] += __shfl_xor(cps[ni], 16, 64);
            cps[ni] += __shfl_xor(cps[ni], 32, 64);
            cns[ni] += __shfl_xor(cns[ni], 16, 64);
            cns[ni] += __shfl_xor(cns[ni], 32, 64);
            if (q == 0) {
                const int cLoc = ni * 16 + cIn;
                if (cps[ni] != 0.f) atomicAdd(&psum[colBase + cLoc], cps[ni]);
                if (cns[ni] != 0.f) atomicAdd(&nsum[colBase + cLoc], cns[ni]);
            }
        }
    }

    // ---- hierarchical done-counter (all RELAXED — no fences) ----
    // __syncthreads() drains vmcnt for ALL waves -> this block's psum/nsum
    // atomics are complete at the coherence point before the increment.
    __syncthreads();
    if (tid == 0) {
        const unsigned stripe = (unsigned)blockIdx.x & 31u;
        const unsigned stripe_target = (unsigned)((NT - (int)stripe + 31) / 32);
        unsigned prev = __hip_atomic_fetch_add(&cnts[(1 + stripe) * 32], 1u,
                                               __ATOMIC_RELAXED, __HIP_MEMORY_SCOPE_AGENT);
        unsigned lf = 0u;
        if (prev == stripe_target - 1u) {
            unsigned ptop = __hip_atomic_fetch_add(&cnts[0], 1u,
                                                   __ATOMIC_RELAXED, __HIP_MEMORY_SCOPE_AGENT);
            lf = (ptop == 31u) ? 1u : 0u;
        }
        lastflag = lf;
    }
    __syncthreads();
    if (lastflag) {
        float a = 0.f;
        for (int i = tid; i < B; i += 256) {
            float pv = atomicAdd(&psum[i], 0.0f);   // coherent returning atomic
            float nv = atomicAdd(&nsum[i], 0.0f);
            if (pv > 0.f && nv > 0.f)
                a += log1pf(pv) * (1.0f / SCALE_POS) + log1pf(nv) * (1.0f / SCALE_NEG);
        }
#pragma unroll
        for (int off = 32; off; off >>= 1) a += __shfl_down(a, off, 64);
        if ((tid & 63) == 0) red[tid >> 6] = a;
        __syncthreads();
        if (tid == 0) out[0] = (red[0] + red[1] + red[2] + red[3]) / (float)B;
    }
}

extern "C" void kernel_launch(void* const* d_in, const int* in_sizes, int n_in,
                              void* d_out, int out_size, void* d_ws, size_t ws_size,
                              hipStream_t stream) {
    const float* feats = (const float*)d_in[0];
    const int* labels = (const int*)d_in[1];
    const int B = in_sizes[1];            // 4096
    const int D = in_sizes[0] / B;        // 1024
    const int nb = B / 128;               // 32
    const int NT = nb * (nb + 1) / 2;     // 528
    const int NH = NT * 2;                // 1056 half-tiles
    const int total4 = B * D / 4;

    char* ws = (char*)d_ws;
    unsigned short* fb16 = (unsigned short*)ws;
    size_t off = (size_t)B * D * sizeof(unsigned short);
    unsigned* minp = (unsigned*)(ws + off); off += (size_t)B * 4;
    unsigned* maxn = (unsigned*)(ws + off); off += (size_t)B * 4;
    float* psum = (float*)(ws + off); off += (size_t)B * 4;
    float* nsum = (float*)(ws + off); off += (size_t)B * 4;
    unsigned* cnts = (unsigned*)(ws + off); off += 8192;  // 2048 u32, zeroed by k_init
    _Float16* simh = (_Float16*)(ws + ((off + 255) & ~(size_t)255));
    float* outp = (float*)d_out;

    k_init<<<(total4 + 255) / 256, 256, 0, stream>>>(feats, fb16, minp, maxn,
                                                     psum, nsum, cnts, total4, B);

    // 1056 blocks x 128 thr -> R10's proven GEMM
    k_gemm_h<<<NH, 128, 0, stream>>>(fb16, labels, minp, maxn, simh, D, nb);

    // 528 blocks x 256 thr, hierarchical relaxed done-counter
    k_sum2f<<<NT, 256, 0, stream>>>(simh, labels, minp, maxn, psum, nsum,
                                    cnts, outp, nb, B, NT);
}

// Round 14
// 137.588 us; speedup vs baseline: 1.8467x; 1.0480x over previous
//
#include <hip/hip_runtime.h>

typedef short short8 __attribute__((ext_vector_type(8)));
typedef _Float16 half8 __attribute__((ext_vector_type(8)));
typedef float floatx4 __attribute__((ext_vector_type(4)));
typedef int intx4 __attribute__((ext_vector_type(4)));
typedef int intx8 __attribute__((ext_vector_type(8)));
typedef __attribute__((address_space(1))) const void gvoid;
typedef __attribute__((address_space(3))) void svoid;

#define SCALE_POS 2.0f
#define SCALE_NEG 40.0f
#define THRESH 0.5f
#define MARGIN 0.1f
#define EPSV 1e-5f

// order-preserving float<->uint map (no NaNs present)
__device__ __forceinline__ unsigned f2ord(float f) {
    unsigned u = __float_as_uint(f);
    return (u & 0x80000000u) ? ~u : (u | 0x80000000u);
}
__device__ __forceinline__ float ord2f(unsigned e) {
    unsigned v = (e & 0x80000000u) ? (e & 0x7fffffffu) : ~e;
    return __uint_as_float(v);
}

#define ORD_POS_INF 0xff800000u   // f2ord(+inf)
#define ORD_NEG_INF 0x007fffffu   // f2ord(-inf)

// ---- kernel 1: fp32 -> fp8 e4m3 (OCP, RNE via HW cvt) + stat/counter init ----
__global__ void k_init(const float* __restrict__ feats,
                       unsigned char* __restrict__ f8,
                       unsigned* __restrict__ minp, unsigned* __restrict__ maxn,
                       float* __restrict__ psum, float* __restrict__ nsum,
                       unsigned* __restrict__ cnts,
                       int total4, int B) {
    int i = blockIdx.x * blockDim.x + threadIdx.x;
    if (i < total4) {
        float4 v = ((const float4*)feats)[i];
        int w = 0;
        w = __builtin_amdgcn_cvt_pk_fp8_f32(v.x, v.y, w, false);  // bytes 0,1
        w = __builtin_amdgcn_cvt_pk_fp8_f32(v.z, v.w, w, true);   // bytes 2,3
        ((int*)f8)[i] = w;
    }
    if (i < B) {
        minp[i] = ORD_POS_INF;
        maxn[i] = ORD_NEG_INF;
        psum[i] = 0.f;
        nsum[i] = 0.f;
    }
    if (i < 2048) cnts[i] = 0;   // top @0; stripe s @ (1+s)*32
}

// =====================================================================
// kernel 2: MX-fp8 symmetric GEMM over 128x64 HALF-tiles (R10 geometry,
// dtype ladder step m148: MX-fp8 K=128 = 1.86x bf16 on this structure).
// 1056 blocks x 128 thr (2 waves, each a full 64x64 worker, 16
// mfma_scale_f32_16x16x128_f8f6f4 per iter, unity E8M0 scales).
// K-loop: 8 iters of K=128. Staging bytes HALVED vs bf16.
// LDS rows are 128B = exact bank period -> XOR-block swizzle applied on
// the GLOBAL source side (LDS side must stay base+lane*16, m104):
//   row r, logical 16B-block b stored at physical block b^(r&7).
// Frag reads then hit each 4-bank group with 2 lanes = free (m136).
// Epilogue (C/D layout is shape-determined, same as 16x16x32): row+col
// stats + fp16 tile store — identical to R13.
// =====================================================================
__global__ void __launch_bounds__(128, 2)
k_gemm_h(const unsigned char* __restrict__ f8,
         const int* __restrict__ labels,
         unsigned* __restrict__ minp_ord,
         unsigned* __restrict__ maxn_ord,
         _Float16* __restrict__ simh,
         int D, int nb) {      // D = 1024 elements = 1024 bytes/row
    __shared__ __align__(16) unsigned char As[128 * 128];  // 16 KB
    __shared__ __align__(16) unsigned char Bs[64 * 128];   // 8 KB
    __shared__ int labR[128], labC[64];

    const int bid = blockIdx.x;
    int t = bid >> 1;
    const int h = bid & 1;
    int rb = 0, rem = t;
    while (rem >= nb - rb) { rem -= nb - rb; ++rb; }
    const int cb = rb + rem;
    const int rowBase = rb * 128;
    const int colBase = cb * 128 + h * 64;

    const int tid = threadIdx.x;        // 0..127
    const int lane = tid & 63;
    const int wave = tid >> 6;          // 0..1 : row half (64 rows each)
    const int q = lane >> 4;
    const int cIn = lane & 15;

    labR[tid] = labels[rowBase + tid];
    if (tid < 64) labC[tid] = labels[colBase + tid];

    // staging: 24 chunks of 1KB (8 rows x 128B). Wave handles 12.
    // chunk c<16 -> As rows 8c..8c+7 ; c>=16 -> Bs rows 8(c-16)..
    // lane i: subrow = i>>3, physical block = i&7, logical = (i&7)^(i>>3)
    const int subrow = lane >> 3;
    const int swz = (lane & 7) ^ subrow;     // logical 16B-block index
    const unsigned char* gP[12];
    unsigned char* lP[12];
#pragma unroll
    for (int j = 0; j < 12; ++j) {
        const int c = wave * 12 + j;
        const int grow = (c < 16) ? (rowBase + c * 8 + subrow)
                                  : (colBase + (c - 16) * 8 + subrow);
        gP[j] = f8 + (size_t)grow * D + swz * 16;
        lP[j] = ((c < 16) ? (As + c * 1024) : (Bs + (c - 16) * 1024)) + lane * 16;
    }

    // fragment LDS offsets: row r, 32B k-group q = logical blocks 2q,2q+1
    // physical p = blk ^ (r&7)
    int aOff0[4], aOff1[4], bOff0[4], bOff1[4];
#pragma unroll
    for (int i = 0; i < 4; ++i) {
        const int rA = wave * 64 + i * 16 + cIn;
        aOff0[i] = rA * 128 + ((2 * q) ^ (rA & 7)) * 16;
        aOff1[i] = rA * 128 + ((2 * q + 1) ^ (rA & 7)) * 16;
        const int rB = i * 16 + cIn;
        bOff0[i] = rB * 128 + ((2 * q) ^ (rB & 7)) * 16;
        bOff1[i] = rB * 128 + ((2 * q + 1) ^ (rB & 7)) * 16;
    }

    floatx4 acc[4][4] = {};

    const int KT = D >> 7;               // 8 iters of K=128
    for (int kt = 0; kt < KT; ++kt) {
        const int kOff = kt * 128;
        __syncthreads();
#pragma unroll
        for (int j = 0; j < 12; ++j)
            __builtin_amdgcn_global_load_lds((gvoid*)(gP[j] + kOff), (svoid*)lP[j], 16, 0, 0);
        __syncthreads();

        intx8 a[4], b[4];
#pragma unroll
        for (int i = 0; i < 4; ++i) {
            intx4 lo = *(const intx4*)(As + aOff0[i]);
            intx4 hi = *(const intx4*)(As + aOff1[i]);
            a[i] = __builtin_shufflevector(lo, hi, 0, 1, 2, 3, 4, 5, 6, 7);
        }
#pragma unroll
        for (int i = 0; i < 4; ++i) {
            intx4 lo = *(const intx4*)(Bs + bOff0[i]);
            intx4 hi = *(const intx4*)(Bs + bOff1[i]);
            b[i] = __builtin_shufflevector(lo, hi, 0, 1, 2, 3, 4, 5, 6, 7);
        }
#pragma unroll
        for (int i = 0; i < 4; ++i)
#pragma unroll
            for (int j = 0; j < 4; ++j)
                acc[i][j] = __builtin_amdgcn_mfma_scale_f32_16x16x128_f8f6f4(
                    a[i], b[j], acc[i][j], 0, 0,       // cbsz=fp8, blgp=fp8
                    0, 0x7f7f7f7f,                     // opsel_a, scale_a (unity E8M0)
                    0, 0x7f7f7f7f);                    // opsel_b, scale_b
    }

    int rLabv[16];
#pragma unroll
    for (int mi = 0; mi < 4; ++mi)
#pragma unroll
        for (int rr = 0; rr < 4; ++rr)
            rLabv[mi * 4 + rr] = labR[wave * 64 + mi * 16 + q * 4 + rr];
    int cLabv[4];
#pragma unroll
    for (int ni = 0; ni < 4; ++ni)
        cLabv[ni] = labC[ni * 16 + cIn];

    // ---- fp16 store: thread-major, 64 contiguous halves (R13 layout) ----
    {
        half8* dst = (half8*)(simh + (size_t)bid * 8192 + (size_t)tid * 64);
#pragma unroll
        for (int mi = 0; mi < 4; ++mi) {
            half8 h0, h1;
#pragma unroll
            for (int ni = 0; ni < 2; ++ni)
#pragma unroll
                for (int rr = 0; rr < 4; ++rr) {
                    h0[ni * 4 + rr] = (_Float16)acc[mi][ni][rr];
                    h1[ni * 4 + rr] = (_Float16)acc[mi][ni + 2][rr];
                }
            dst[mi * 2] = h0;
            dst[mi * 2 + 1] = h1;
        }
    }

    // ---- row stats ----
#pragma unroll
    for (int mi = 0; mi < 4; ++mi)
#pragma unroll
        for (int rr = 0; rr < 4; ++rr) {
            const int rLoc = wave * 64 + mi * 16 + q * 4 + rr;
            const int rLab = rLabv[mi * 4 + rr];
            float vmin = 1e30f, vmax = -1e30f;
#pragma unroll
            for (int ni = 0; ni < 4; ++ni) {
                float s = acc[mi][ni][rr];
                if (rLab == cLabv[ni]) {
                    if (s < 1.0f - EPSV) vmin = fminf(vmin, s);
                } else {
                    vmax = fmaxf(vmax, s);
                }
            }
#pragma unroll
            for (int off = 8; off; off >>= 1) {
                vmin = fminf(vmin, __shfl_xor(vmin, off, 16));
                vmax = fmaxf(vmax, __shfl_xor(vmax, off, 16));
            }
            if (cIn == 0) {
                if (vmin < 1e30f) atomicMin(&minp_ord[rowBase + rLoc], f2ord(vmin));
                if (vmax > -1e30f) atomicMax(&maxn_ord[rowBase + rLoc], f2ord(vmax));
            }
        }

    // ---- col stats via symmetry (off-diagonal tiles only) ----
    if (rb != cb) {
#pragma unroll
        for (int ni = 0; ni < 4; ++ni) {
            const int cLab = cLabv[ni];
            float vmin = 1e30f, vmax = -1e30f;
#pragma unroll
            for (int mi = 0; mi < 4; ++mi)
#pragma unroll
                for (int rr = 0; rr < 4; ++rr) {
                    float s = acc[mi][ni][rr];
                    if (rLabv[mi * 4 + rr] == cLab) {
                        if (s < 1.0f - EPSV) vmin = fminf(vmin, s);
                    } else {
                        vmax = fmaxf(vmax, s);
                    }
                }
            vmin = fminf(vmin, __shfl_xor(vmin, 16, 64));
            vmin = fminf(vmin, __shfl_xor(vmin, 32, 64));
            vmax = fmaxf(vmax, __shfl_xor(vmax, 16, 64));
            vmax = fmaxf(vmax, __shfl_xor(vmax, 32, 64));
            if (q == 0) {
                const int cLoc = ni * 16 + cIn;
                if (vmin < 1e30f) atomicMin(&minp_ord[colBase + cLoc], f2ord(vmin));
                if (vmax > -1e30f) atomicMax(&maxn_ord[colBase + cLoc], f2ord(vmax));
            }
        }
    }
}

// =====================================================================
// kernel 3 (unchanged from R13): pass 2, 528 blocks x 256 threads +
// fused final reduction behind the hierarchical RELAXED done-counter.
// =====================================================================
__global__ void __launch_bounds__(256)
k_sum2f(const _Float16* __restrict__ simh,
        const int* __restrict__ labels,
        const unsigned* __restrict__ minp_ord,
        const unsigned* __restrict__ maxn_ord,
        float* __restrict__ psum, float* __restrict__ nsum,
        unsigned* __restrict__ cnts,   // top @0; stripe s @ (1+s)*32
        float* __restrict__ out,
        int nb, int B, int NT) {
    __shared__ int labR[128], labC[128];
    __shared__ float mpR[128], mnR[128], mpC[128], mnC[128];
    __shared__ float red[4];
    __shared__ unsigned lastflag;

    int t = blockIdx.x;
    int rb = 0, rem = t;
    while (rem >= nb - rb) { rem -= nb - rb; ++rb; }
    const int cb = rb + rem;
    const int rowBase = rb * 128;

    const int tid = threadIdx.x;
    const int sub = tid >> 7;
    const int stid = tid & 127;
    const int wave = stid >> 6;
    const int lane = tid & 63;
    const int q = lane >> 4;
    const int cIn = lane & 15;
    const int colBase = cb * 128 + sub * 64;

    if (tid < 128) {
        labR[tid] = labels[rowBase + tid];
        mpR[tid] = ord2f(minp_ord[rowBase + tid]) - MARGIN;   // neg kept if s > this
        mnR[tid] = ord2f(maxn_ord[rowBase + tid]) + MARGIN;   // pos kept if s < this
    } else {
        const int j = tid - 128;
        labC[j] = labels[cb * 128 + j];
        mpC[j] = ord2f(minp_ord[cb * 128 + j]) - MARGIN;
        mnC[j] = ord2f(maxn_ord[cb * 128 + j]) + MARGIN;
    }
    __syncthreads();

    int cLabv[4];
    float mpCv[4], mnCv[4];
#pragma unroll
    for (int ni = 0; ni < 4; ++ni) {
        const int j = sub * 64 + ni * 16 + cIn;
        cLabv[ni] = labC[j];
        mpCv[ni] = mpC[j];
        mnCv[ni] = mnC[j];
    }

    const half8* src = (const half8*)(simh + (size_t)(2 * t + sub) * 8192 + (size_t)stid * 64);
    half8 hv[8];
#pragma unroll
    for (int v = 0; v < 8; ++v) hv[v] = src[v];

    float cps[4] = {}, cns[4] = {};
    const bool offd = (rb != cb);

#pragma unroll
    for (int mi = 0; mi < 4; ++mi)
#pragma unroll
        for (int rr = 0; rr < 4; ++rr) {
            const int rLoc = wave * 64 + mi * 16 + q * 4 + rr;
            const int rLab = labR[rLoc];
            const float gateN = mpR[rLoc];
            const float gateP = mnR[rLoc];
            float rp = 0.f, rn = 0.f;
#pragma unroll
            for (int ni = 0; ni < 4; ++ni) {
                const int idx = mi * 16 + ni * 4 + rr;
                const float s = (float)hv[idx >> 3][idx & 7];
                if (rLab == cLabv[ni]) {
                    if (s < 1.0f - EPSV) {
                        float ev = __expf(-SCALE_POS * (s - THRESH));
                        if (s < gateP) rp += ev;
                        if (offd && s < mnCv[ni]) cps[ni] += ev;
                    }
                } else {
                    float ev = __expf(SCALE_NEG * (s - THRESH));
                    if (s > gateN) rn += ev;
                    if (offd && s > mpCv[ni]) cns[ni] += ev;
                }
            }
#pragma unroll
            for (int off = 8; off; off >>= 1) {
                rp += __shfl_xor(rp, off, 16);
                rn += __shfl_xor(rn, off, 16);
            }
            if (cIn == 0) {
                if (rp != 0.f) atomicAdd(&psum[rowBase + rLoc], rp);
                if (rn != 0.f) atomicAdd(&nsum[rowBase + rLoc], rn);
            }
        }
    if (offd) {
#pragma unroll
        for (int ni = 0; ni < 4; ++ni) {
            cps[ni] += __shfl_xor(cps[ni], 16, 64);
            cps[ni] += __shfl_xor(cps[ni], 32, 64);
            cns[ni] += __shfl_xor(cns[ni], 16, 64);
            cns[ni] += __shfl_xor(cns[ni], 32, 64);
            if (q == 0) {
                const int cLoc = ni * 16 + cIn;
                if (cps[ni] != 0.f) atomicAdd(&psum[colBase + cLoc], cps[ni]);
                if (cns[ni] != 0.f) atomicAdd(&nsum[colBase + cLoc], cns[ni]);
            }
        }
    }

    // ---- hierarchical done-counter (all RELAXED — no fences) ----
    __syncthreads();
    if (tid == 0) {
        const unsigned stripe = (unsigned)blockIdx.x & 31u;
        const unsigned stripe_target = (unsigned)((NT - (int)stripe + 31) / 32);
        unsigned prev = __hip_atomic_fetch_add(&cnts[(1 + stripe) * 32], 1u,
                                               __ATOMIC_RELAXED, __HIP_MEMORY_SCOPE_AGENT);
        unsigned lf = 0u;
        if (prev == stripe_target - 1u) {
            unsigned ptop = __hip_atomic_fetch_add(&cnts[0], 1u,
                                                   __ATOMIC_RELAXED, __HIP_MEMORY_SCOPE_AGENT);
            lf = (ptop == 31u) ? 1u : 0u;
        }
        lastflag = lf;
    }
    __syncthreads();
    if (lastflag) {
        float a = 0.f;
        for (int i = tid; i < B; i += 256) {
            float pv = atomicAdd(&psum[i], 0.0f);   // coherent returning atomic
            float nv = atomicAdd(&nsum[i], 0.0f);
            if (pv > 0.f && nv > 0.f)
                a += log1pf(pv) * (1.0f / SCALE_POS) + log1pf(nv) * (1.0f / SCALE_NEG);
        }
#pragma unroll
        for (int off = 32; off; off >>= 1) a += __shfl_down(a, off, 64);
        if ((tid & 63) == 0) red[tid >> 6] = a;
        __syncthreads();
        if (tid == 0) out[0] = (red[0] + red[1] + red[2] + red[3]) / (float)B;
    }
}

extern "C" void kernel_launch(void* const* d_in, const int* in_sizes, int n_in,
                              void* d_out, int out_size, void* d_ws, size_t ws_size,
                              hipStream_t stream) {
    const float* feats = (const float*)d_in[0];
    const int* labels = (const int*)d_in[1];
    const int B = in_sizes[1];            // 4096
    const int D = in_sizes[0] / B;        // 1024
    const int nb = B / 128;               // 32
    const int NT = nb * (nb + 1) / 2;     // 528
    const int NH = NT * 2;                // 1056 half-tiles
    const int total4 = B * D / 4;

    char* ws = (char*)d_ws;
    unsigned char* f8 = (unsigned char*)ws;
    size_t off = (size_t)B * D;           // 4 MB fp8
    unsigned* minp = (unsigned*)(ws + off); off += (size_t)B * 4;
    unsigned* maxn = (unsigned*)(ws + off); off += (size_t)B * 4;
    float* psum = (float*)(ws + off); off += (size_t)B * 4;
    float* nsum = (float*)(ws + off); off += (size_t)B * 4;
    unsigned* cnts = (unsigned*)(ws + off); off += 8192;  // 2048 u32, zeroed by k_init
    _Float16* simh = (_Float16*)(ws + ((off + 255) & ~(size_t)255));
    float* outp = (float*)d_out;

    k_init<<<(total4 + 255) / 256, 256, 0, stream>>>(feats, f8, minp, maxn,
                                                     psum, nsum, cnts, total4, B);

    // 1056 blocks x 128 thr — MX-fp8 K=128 GEMM
    k_gemm_h<<<NH, 128, 0, stream>>>(f8, labels, minp, maxn, simh, D, nb);

    // 528 blocks x 256 thr, hierarchical relaxed done-counter
    k_sum2f<<<NT, 256, 0, stream>>>(simh, labels, minp, maxn, psum, nsum,
                                    cnts, outp, nb, B, NT);
}